// Round 14
// baseline (403.606 us; speedup 1.0000x reference)
//
#include <hip/hip_runtime.h>

#define N_NODES 100000
#define N_EDGES 1600000
#define DIN 128
#define DOUT 128
#define N_SUP 2
#define E_TOT (N_SUP * N_EDGES)          // 3,200,000

#define BIN_ROWS 128
#define BSHIFT 7
#define NBINS ((N_NODES + BIN_ROWS - 1) / BIN_ROWS)    // 782
#define CAP 4608     // bin capacity: mean 4096, sigma 64 -> +8 sigma

#define SC_EPT 16
#define SC_BLOCK 256
#define SC_CHUNK (SC_EPT * SC_BLOCK)                    // 4096
#define NBLK_SC ((E_TOT + SC_CHUNK - 1) / SC_CHUNK)     // 782

#define GEMM_ROWS 128
#define NBLK_GEMM ((N_NODES + GEMM_ROWS - 1) / GEMM_ROWS)   // 782
#define LDK 136      // padded LDS k-stride in bf16 units (odd multiple of 8)

#define GEMM_SMEM (GEMM_ROWS * LDK * 2)                 // 34,816 (x-stage only)
#define SCAT_SMEM (2 * NBINS * 4)                       //  6,256
#define SORT_SMEM (CAP * 8 + 2 * BIN_ROWS * 4)          // 37,888
#define SMEM_A ((GEMM_SMEM > SCAT_SMEM) ? GEMM_SMEM : SCAT_SMEM)   // 34,816
#define SMEM_B ((GEMM_SMEM > SORT_SMEM) ? GEMM_SMEM : SORT_SMEM)   // 37,888

typedef float        f32x2 __attribute__((ext_vector_type(2)));
typedef float        f32x4 __attribute__((ext_vector_type(4)));
typedef unsigned int u32;
typedef u32          u32x2 __attribute__((ext_vector_type(2)));
typedef u32          u32x4 __attribute__((ext_vector_type(4)));
typedef short        bf16x8 __attribute__((ext_vector_type(8)));

// round-to-nearest-even fp32 -> bf16 pair packed in one u32 (lo = even idx)
static __device__ __forceinline__ u32 pack_bf16x2(float lo, float hi) {
    u32 ul = __float_as_uint(lo);
    u32 uh = __float_as_uint(hi);
    ul = (ul + 0x7FFFu + ((ul >> 16) & 1u)) >> 16;
    uh = ((uh + 0x7FFFu + ((uh >> 16) & 1u)) >> 16) << 16;
    return ul | uh;
}

// ---------------------------------------------------------------------------
// Fused: blocks 0..1 convert w -> wT packed bf16; blocks 2..5 init
// bin_cursor[b] = b*CAP. (Verified R11/R13.)
// ---------------------------------------------------------------------------
__global__ __launch_bounds__(256) void wconv_init_kernel(const float* __restrict__ w,
                                                         u32* __restrict__ wTb,
                                                         int* __restrict__ bin_cursor) {
    if (blockIdx.x >= N_SUP) {
        const int b = (blockIdx.x - N_SUP) * 256 + threadIdx.x;
        if (b < NBINS) bin_cursor[b] = b * CAP;
        return;
    }
    const int s = blockIdx.x;
    const int n = threadIdx.x >> 1;
    const int kh = (threadIdx.x & 1) * 64;
    const float* wp = w + (size_t)s * DIN * DOUT + n;
    u32 o[32];
    #pragma unroll
    for (int j = 0; j < 32; j++) {
        const float lo = wp[(size_t)(kh + 2 * j) * DOUT];
        const float hi = wp[(size_t)(kh + 2 * j + 1) * DOUT];
        o[j] = pack_bf16x2(lo, hi);
    }
    u32* op = wTb + ((size_t)s * 128 + n) * 64 + kh / 2;
    #pragma unroll
    for (int j = 0; j < 8; j++)
        *(u32x4*)(op + j * 4) = *(u32x4*)&o[j * 4];
}

// ---------------------------------------------------------------------------
// GEMM body, LDS-slim (34.8 KB vs R13's 69.6): same MFMA math, but
// (a) B-fragments read directly from wTb (32 KB per support = L1-sized,
//     shared by all blocks -> L1/L2-hot; saves the 34.8 KB W-stage);
// (b) 2-pass epilogue through a [64][129] fp32 buffer (33 KB) aliasing the
//     x-stage: waves 0-1's rows then waves 2-3's rows. Conflict-free map:
//     row = t&63 (2-way banks), word-quarter = t>>6 (full-line 64B stores).
// Halved LDS doubles fused-launch co-residency (2 -> 4 blocks/CU), giving
// the co-scheduled memory-bound scatter/sort halves their TLP back (R12
// lesson: occupancy IS bandwidth for latency-bound work).
// ---------------------------------------------------------------------------
static __device__ __forceinline__ void gemm_body(char* smem, int bidx, int s,
                                                 const float* __restrict__ x,
                                                 const u32* __restrict__ wTb,
                                                 u32* __restrict__ pre) {
    typedef unsigned short (*xstage_p)[LDK];
    xstage_p xs = (xstage_p)smem;                 // [128][LDK] = 34,816 B
    float (*epi)[129] = (float (*)[129])smem;     // [64][129]  = 33,024 B

    const int row0 = bidx * GEMM_ROWS;
    const int t = threadIdx.x;
    const int lane = t & 63;
    const int wv = t >> 6;

    // stage x tile (rows row0..row0+127): fp32 -> packed bf16 LDS rows
    {
        const int r = t >> 1;
        const int half = t & 1;               // k 0..63 / 64..127
        const int gr = row0 + r;
        u32* dst = (u32*)&xs[r][half * 64];
        u32 o[32];
        if (gr < N_NODES) {
            const float* p = x + (size_t)gr * DIN + half * 64;
            #pragma unroll
            for (int j = 0; j < 16; j++) {
                const f32x4 a = *(const f32x4*)(p + j * 4);
                o[2 * j]     = pack_bf16x2(a.x, a.y);
                o[2 * j + 1] = pack_bf16x2(a.z, a.w);
            }
        } else {
            #pragma unroll
            for (int j = 0; j < 32; j++) o[j] = 0;
        }
        #pragma unroll
        for (int j = 0; j < 8; j++)
            *(u32x4*)(dst + j * 4) = *(u32x4*)&o[j * 4];
    }
    __syncthreads();

    const int q = lane >> 4;       // quad: k sub-block
    const int ml = lane & 15;      // row within m-tile / col within n-tile
    const int m0 = wv * 32;

    f32x4 acc[2][8];
    #pragma unroll
    for (int mt = 0; mt < 2; mt++)
        #pragma unroll
        for (int nt = 0; nt < 8; nt++) acc[mt][nt] = (f32x4){0.f, 0.f, 0.f, 0.f};

    // B-fragment base for this lane: row (nt*16+ml), k-words (kt*16 + q*4)
    const u32* wbase = wTb + (size_t)s * 128 * 64 + (size_t)ml * 64 + q * 4;

    #pragma unroll
    for (int kt = 0; kt < 4; kt++) {
        const int k0 = kt * 32 + q * 8;
        const bf16x8 a0 = *(const bf16x8*)&xs[m0 + ml][k0];
        const bf16x8 a1 = *(const bf16x8*)&xs[m0 + 16 + ml][k0];
        #pragma unroll
        for (int nt = 0; nt < 8; nt++) {
            const bf16x8 b = *(const bf16x8*)(wbase + (size_t)nt * 16 * 64 + kt * 16);
            acc[0][nt] = __builtin_amdgcn_mfma_f32_16x16x32_bf16(a0, b, acc[0][nt], 0, 0, 0);
            acc[1][nt] = __builtin_amdgcn_mfma_f32_16x16x32_bf16(a1, b, acc[1][nt], 0, 0, 0);
        }
    }

    // 2-pass epilogue: rows 0-63 (waves 0,1) then rows 64-127 (waves 2,3)
    #pragma unroll
    for (int p = 0; p < 2; p++) {
        __syncthreads();   // pass 0: xs reads done; pass 1: epi reads done
        if ((wv >> 1) == p) {
            const int m0l = (wv & 1) * 32;
            #pragma unroll
            for (int mt = 0; mt < 2; mt++)
                #pragma unroll
                for (int nt = 0; nt < 8; nt++)
                    #pragma unroll
                    for (int r = 0; r < 4; r++)
                        epi[m0l + mt * 16 + q * 4 + r][nt * 16 + ml] = acc[mt][nt][r];
        }
        __syncthreads();
        // pack + store: row = t&63, word-quarter = t>>6 (16 u32 each)
        {
            const int row = t & 63;
            const int qi = t >> 6;
            const int gr = row0 + p * 64 + row;
            if (gr < N_NODES) {
                u32 ov[16];
                #pragma unroll
                for (int j = 0; j < 16; j++)
                    ov[j] = pack_bf16x2(epi[row][qi * 32 + 2 * j],
                                        epi[row][qi * 32 + 2 * j + 1]);
                u32* op = pre + ((size_t)s * N_NODES + gr) * 64 + qi * 16;
                #pragma unroll
                for (int j = 0; j < 4; j++)
                    __builtin_nontemporal_store(*(u32x4*)&ov[j * 4], (u32x4*)(op + j * 4));
            }
        }
    }
}

// ---------------------------------------------------------------------------
// Binscatter body: BYTE-IDENTICAL content to R13 (block-local contiguous
// runs -> coalesced writes; R8 lesson).
// ---------------------------------------------------------------------------
static __device__ __forceinline__ void scatter_body(char* smem, int bidx,
                                                    const int* __restrict__ rows,
                                                    const int* __restrict__ cols,
                                                    const float* __restrict__ vals,
                                                    int* __restrict__ bin_cursor,
                                                    u32x2* __restrict__ edata) {
    int* lcnt = (int*)smem;
    int* lbase = lcnt + NBINS;
    const int t = threadIdx.x;
    for (int i = t; i < NBINS; i += 256) lcnt[i] = 0;
    __syncthreads();

    const int base = bidx * SC_CHUNK;
    int bin[SC_EPT], lpos[SC_EPT];
    u32x2 pay[SC_EPT];
    #pragma unroll
    for (int j = 0; j < SC_EPT; j++) {
        const int i = base + j * 256 + t;
        if (i < E_TOT) {
            const int r = __builtin_nontemporal_load(rows + i);
            const int c = __builtin_nontemporal_load(cols + i);
            const float v = __builtin_nontemporal_load(vals + i);
            const int b = r >> BSHIFT;
            bin[j] = b;
            lpos[j] = atomicAdd(&lcnt[b], 1);
            pay[j].x = (u32)(c + ((i >= N_EDGES) ? N_NODES : 0)) |
                       ((u32)(r & (BIN_ROWS - 1)) << 18);
            pay[j].y = __float_as_uint(v);
        } else {
            bin[j] = -1;
        }
    }
    __syncthreads();
    for (int b = t; b < NBINS; b += 256) {
        const int c = lcnt[b];
        if (c) lbase[b] = atomicAdd(&bin_cursor[b], c);
    }
    __syncthreads();
    #pragma unroll
    for (int j = 0; j < SC_EPT; j++) {
        if (bin[j] >= 0) edata[lbase[bin[j]] + lpos[j]] = pay[j];
    }
}

// ---------------------------------------------------------------------------
// Binsort body: BYTE-IDENTICAL content to R13 (in-place via LDS stage,
// emits {beg,end} int2 per row).
// ---------------------------------------------------------------------------
static __device__ __forceinline__ void sort_body(char* smem, int b,
                                                 u32x2* __restrict__ edata,
                                                 const int* __restrict__ bin_cursor,
                                                 int2* __restrict__ rbe) {
    u32x2* ebuf = (u32x2*)smem;                    // CAP * 8 = 36,864 B
    int* rcnt = (int*)(smem + CAP * 8);            // 512 B
    int* rscan = rcnt + BIN_ROWS;                  // 512 B
    const int t = threadIdx.x;
    const int beg = b * CAP;
    const int cnt = min(bin_cursor[b] - beg, CAP);

    for (int e = t; e < cnt; e += 256)
        ebuf[e] = __builtin_nontemporal_load(edata + beg + e);
    if (t < BIN_ROWS) rcnt[t] = 0;
    __syncthreads();

    for (int e = t; e < cnt; e += 256)
        atomicAdd(&rcnt[ebuf[e].x >> 18], 1);
    __syncthreads();

    const int v = (t < BIN_ROWS) ? rcnt[t] : 0;
    if (t < BIN_ROWS) rscan[t] = v;
    __syncthreads();
    #pragma unroll
    for (int off = 1; off < BIN_ROWS; off <<= 1) {
        const int u = (t < BIN_ROWS && t >= off) ? rscan[t - off] : 0;
        __syncthreads();
        if (t < BIN_ROWS) rscan[t] += u;
        __syncthreads();
    }
    if (t < BIN_ROWS) {
        const int ex = rscan[t] - v;
        rcnt[t] = ex;                       // reuse as cursor
        const int row = b * BIN_ROWS + t;
        if (row < N_NODES) {
            int2 be;
            be.x = beg + ex;
            be.y = beg + ex + v;
            rbe[row] = be;
        }
    }
    __syncthreads();
    for (int e = t; e < cnt; e += 256) {
        const u32x2 d = ebuf[e];
        const int pos = beg + atomicAdd(&rcnt[d.x >> 18], 1);
        u32x2 o;
        o.x = d.x & 0x3FFFFu;
        o.y = d.y;
        edata[pos] = o;
    }
}

// ---------------------------------------------------------------------------
// Launch A: even blocks = binscatter, odd blocks = GEMM s=0. LDS union
// 34.8 KB -> 4 blocks/CU (was 2 at 69.6 KB in R13).
// ---------------------------------------------------------------------------
__global__ __launch_bounds__(256) void fusedA_kernel(const int* __restrict__ rows,
                                                     const int* __restrict__ cols,
                                                     const float* __restrict__ vals,
                                                     int* __restrict__ bin_cursor,
                                                     u32x2* __restrict__ edata,
                                                     const float* __restrict__ x,
                                                     const u32* __restrict__ wTb,
                                                     u32* __restrict__ pre) {
    __shared__ alignas(16) char smem[SMEM_A];
    const int bid = blockIdx.x;
    if (bid & 1) gemm_body(smem, bid >> 1, 0, x, wTb, pre);
    else         scatter_body(smem, bid >> 1, rows, cols, vals, bin_cursor, edata);
}

// ---------------------------------------------------------------------------
// Launch B: even blocks = binsort, odd blocks = GEMM s=1. LDS union
// 37.9 KB -> 4 blocks/CU.
// ---------------------------------------------------------------------------
__global__ __launch_bounds__(256) void fusedB_kernel(u32x2* __restrict__ edata,
                                                     const int* __restrict__ bin_cursor,
                                                     int2* __restrict__ rbe,
                                                     const float* __restrict__ x,
                                                     const u32* __restrict__ wTb,
                                                     u32* __restrict__ pre) {
    __shared__ alignas(16) char smem[SMEM_B];
    const int bid = blockIdx.x;
    if (bid & 1) gemm_body(smem, bid >> 1, 1, x, wTb, pre);
    else         sort_body(smem, bid >> 1, edata, bin_cursor, rbe);
}

// ---------------------------------------------------------------------------
// Gather-accumulate: BYTE-IDENTICAL to R9/R13 (verified 128 us, at the
// ~10.4 B/cyc/CU narrow-coalesced random-access roofline).
// ---------------------------------------------------------------------------
__global__ __launch_bounds__(256, 6) void gather_kernel(const u32* __restrict__ pre,
                                                        const u32x2* __restrict__ edata,
                                                        const int2* __restrict__ rbe,
                                                        const float* __restrict__ bias,
                                                        float* __restrict__ out) {
    const int lane = threadIdx.x & 63;
    const int wid = threadIdx.x >> 6;
    const int row = blockIdx.x * 4 + wid;
    if (row >= N_NODES) return;

    const int2 be = rbe[row];
    int e = be.x;
    const int end = be.y;

    float ax = 0.f, ay = 0.f;

    if (e + 8 <= end) {
        u32x2 d[8];
        #pragma unroll
        for (int j = 0; j < 8; j++)
            d[j] = __builtin_nontemporal_load(edata + e + j);
        for (;;) {
            u32 u[8];
            #pragma unroll
            for (int j = 0; j < 8; j++)
                u[j] = pre[(u32)((d[j].x << 6) + (u32)lane)];
            const int en = e + 8;
            const bool more = (en + 8 <= end);   // wave-uniform
            u32x2 dn[8];
            if (more) {
                #pragma unroll
                for (int j = 0; j < 8; j++)
                    dn[j] = __builtin_nontemporal_load(edata + en + j);
            }
            #pragma unroll
            for (int j = 0; j < 8; j++) {
                const float v = __uint_as_float(d[j].y);
                ax = fmaf(v, __uint_as_float(u[j] << 16), ax);
                ay = fmaf(v, __uint_as_float(u[j] & 0xFFFF0000u), ay);
            }
            e = en;
            if (!more) break;
            #pragma unroll
            for (int j = 0; j < 8; j++) d[j] = dn[j];
        }
    }
    // mid: 4 edges per batch
    for (; e + 4 <= end; e += 4) {
        u32x2 d[4];
        #pragma unroll
        for (int j = 0; j < 4; j++)
            d[j] = __builtin_nontemporal_load(edata + e + j);
        u32 u[4];
        #pragma unroll
        for (int j = 0; j < 4; j++)
            u[j] = pre[(u32)((d[j].x << 6) + (u32)lane)];
        #pragma unroll
        for (int j = 0; j < 4; j++) {
            const float v = __uint_as_float(d[j].y);
            ax = fmaf(v, __uint_as_float(u[j] << 16), ax);
            ay = fmaf(v, __uint_as_float(u[j] & 0xFFFF0000u), ay);
        }
    }
    // tail
    for (; e < end; e++) {
        const u32x2 d = __builtin_nontemporal_load(edata + e);
        const u32 u = pre[(u32)((d.x << 6) + (u32)lane)];
        const float v = __uint_as_float(d.y);
        ax = fmaf(v, __uint_as_float(u << 16), ax);
        ay = fmaf(v, __uint_as_float(u & 0xFFFF0000u), ay);
    }

    const float2 b = *(const float2*)(bias + lane * 2);
    f32x2 r;
    r.x = fmaxf(ax + b.x, 0.f);
    r.y = fmaxf(ay + b.y, 0.f);
    __builtin_nontemporal_store(r, (f32x2*)(out + (size_t)row * DOUT + lane * 2));
}

extern "C" void kernel_launch(void* const* d_in, const int* in_sizes, int n_in,
                              void* d_out, int out_size, void* d_ws, size_t ws_size,
                              hipStream_t stream) {
    (void)in_sizes; (void)n_in; (void)out_size; (void)ws_size;
    const float* x        = (const float*)d_in[0];   // [N, 128]
    const float* w        = (const float*)d_in[1];   // [2, 128, 128]
    const float* bias     = (const float*)d_in[2];   // [128]
    const float* sup_vals = (const float*)d_in[3];   // [2, E] flat
    const int*   sup_rows = (const int*)d_in[4];     // [2, E] flat
    const int*   sup_cols = (const int*)d_in[5];     // [2, E] flat
    float* out = (float*)d_out;                      // [N, 128]

    // ws layout: pre | edata (padded bins) | rbe | bin_cursor | wTb (~81 MB)
    char* ws = (char*)d_ws;
    u32*   pre       = (u32*)ws;                                        // 51.2 MB
    u32x2* edata     = (u32x2*)(ws + (size_t)N_SUP * N_NODES * 64 * 4); // 28.8 MB
    int2*  rbe       = (int2*)((char*)edata + (size_t)NBINS * CAP * 8); // 800 KB
    int*   bin_cursor= (int*)(rbe + N_NODES);                           // NBINS
    u32*   wTb       = (u32*)(bin_cursor + NBINS + 2);                  // 64 KB

    // 1. w -> transposed bf16 + bin_cursor init (fused)
    wconv_init_kernel<<<N_SUP + (NBINS + 255) / 256, 256, 0, stream>>>(w, wTb, bin_cursor);
    // 2. Launch A: binscatter (even blocks) overlapped with GEMM s=0 (odd)
    fusedA_kernel<<<NBLK_SC + NBLK_GEMM, 256, 0, stream>>>(sup_rows, sup_cols, sup_vals,
                                                           bin_cursor, edata, x, wTb, pre);
    // 3. Launch B: binsort (even blocks) overlapped with GEMM s=1 (odd)
    fusedB_kernel<<<NBINS + NBLK_GEMM, 256, 0, stream>>>(edata, bin_cursor, rbe, x, wTb, pre);
    // 4. row gather + bias + ReLU (no atomics)
    gather_kernel<<<(N_NODES + 3) / 4, 256, 0, stream>>>(pre, edata, rbe, bias, out);
}

// Round 15
// 363.847 us; speedup vs baseline: 1.1093x; 1.1093x over previous
//
#include <hip/hip_runtime.h>

#define N_NODES 100000
#define N_EDGES 1600000
#define DIN 128
#define DOUT 128
#define N_SUP 2
#define E_TOT (N_SUP * N_EDGES)          // 3,200,000

#define BIN_ROWS 128
#define BSHIFT 7
#define NBINS ((N_NODES + BIN_ROWS - 1) / BIN_ROWS)    // 782
#define CAP 4608     // bin capacity: mean 4096, sigma 64 -> +8 sigma

#define SC_EPT 16
#define SC_BLOCK 256
#define SC_CHUNK (SC_EPT * SC_BLOCK)                    // 4096
#define NBLK_SC ((E_TOT + SC_CHUNK - 1) / SC_CHUNK)     // 782

#define GEMM_ROWS 128
#define NBLK_GEMM ((N_NODES + GEMM_ROWS - 1) / GEMM_ROWS)   // 782
#define LDK 136      // padded LDS k-stride in bf16 units (odd multiple of 8)
#define GEMM_SMEM (2 * GEMM_ROWS * LDK * 2)             // 69,632 (R13-verified)
#define SORT_SMEM (CAP * 8 + 2 * BIN_ROWS * 4)          // 37,888
#define SCAT_SMEM (2 * NBINS * 4)                       //  6,256

typedef float        f32x2 __attribute__((ext_vector_type(2)));
typedef float        f32x4 __attribute__((ext_vector_type(4)));
typedef unsigned int u32;
typedef u32          u32x2 __attribute__((ext_vector_type(2)));
typedef u32          u32x4 __attribute__((ext_vector_type(4)));
typedef short        bf16x8 __attribute__((ext_vector_type(8)));

// round-to-nearest-even fp32 -> bf16 pair packed in one u32 (lo = even idx)
static __device__ __forceinline__ u32 pack_bf16x2(float lo, float hi) {
    u32 ul = __float_as_uint(lo);
    u32 uh = __float_as_uint(hi);
    ul = (ul + 0x7FFFu + ((ul >> 16) & 1u)) >> 16;
    uh = ((uh + 0x7FFFu + ((uh >> 16) & 1u)) >> 16) << 16;
    return ul | uh;
}

// ---------------------------------------------------------------------------
// GEMM body: R13-VERIFIED content (W staged in LDS, single-pass epilogue
// aliasing the stage). pre[s] = x @ w[s] in bf16 MFMA, fp32 accumulate.
// ---------------------------------------------------------------------------
static __device__ __forceinline__ void gemm_body(char* smem, int bidx, int s,
                                                 const float* __restrict__ x,
                                                 const u32* __restrict__ wTb,
                                                 u32* __restrict__ pre) {
    typedef unsigned short (*stage_p)[GEMM_ROWS][LDK];
    stage_p stage = (stage_p)smem;
    float (*epi)[129] = (float (*)[129])smem;

    const int row0 = bidx * GEMM_ROWS;
    const int t = threadIdx.x;
    const int lane = t & 63;
    const int wv = t >> 6;

    // stage x tile (rows row0..row0+127): fp32 -> packed bf16 LDS rows
    {
        const int r = t >> 1;
        const int half = t & 1;               // k 0..63 / 64..127
        const int gr = row0 + r;
        u32* dst = (u32*)&stage[0][r][half * 64];
        u32 o[32];
        if (gr < N_NODES) {
            const float* p = x + (size_t)gr * DIN + half * 64;
            #pragma unroll
            for (int j = 0; j < 16; j++) {
                const f32x4 a = *(const f32x4*)(p + j * 4);
                o[2 * j]     = pack_bf16x2(a.x, a.y);
                o[2 * j + 1] = pack_bf16x2(a.z, a.w);
            }
        } else {
            #pragma unroll
            for (int j = 0; j < 32; j++) o[j] = 0;
        }
        #pragma unroll
        for (int j = 0; j < 8; j++)
            *(u32x4*)(dst + j * 4) = *(u32x4*)&o[j * 4];
        // stage wT[s] (128 n-rows x 128 k)
        const u32* wp = wTb + ((size_t)s * 128 + r) * 64 + half * 32;
        u32* wdst = (u32*)&stage[1][r][half * 64];
        #pragma unroll
        for (int j = 0; j < 8; j++)
            *(u32x4*)(wdst + j * 4) = *(const u32x4*)(wp + j * 4);
    }
    __syncthreads();

    const int q = lane >> 4;       // quad: k sub-block
    const int ml = lane & 15;      // row within m-tile / col within n-tile
    const int m0 = wv * 32;

    f32x4 acc[2][8];
    #pragma unroll
    for (int mt = 0; mt < 2; mt++)
        #pragma unroll
        for (int nt = 0; nt < 8; nt++) acc[mt][nt] = (f32x4){0.f, 0.f, 0.f, 0.f};

    #pragma unroll
    for (int kt = 0; kt < 4; kt++) {
        const int k0 = kt * 32 + q * 8;
        const bf16x8 a0 = *(const bf16x8*)&stage[0][m0 + ml][k0];
        const bf16x8 a1 = *(const bf16x8*)&stage[0][m0 + 16 + ml][k0];
        #pragma unroll
        for (int nt = 0; nt < 8; nt++) {
            const bf16x8 b = *(const bf16x8*)&stage[1][nt * 16 + ml][k0];
            acc[0][nt] = __builtin_amdgcn_mfma_f32_16x16x32_bf16(a0, b, acc[0][nt], 0, 0, 0);
            acc[1][nt] = __builtin_amdgcn_mfma_f32_16x16x32_bf16(a1, b, acc[1][nt], 0, 0, 0);
        }
    }
    __syncthreads();   // done reading stage; epi aliases it

    // C-layout (col=lane&15, row=quad*4+reg) -> LDS fp32 [row][feat]
    #pragma unroll
    for (int mt = 0; mt < 2; mt++)
        #pragma unroll
        for (int nt = 0; nt < 8; nt++)
            #pragma unroll
            for (int r = 0; r < 4; r++)
                epi[m0 + mt * 16 + q * 4 + r][nt * 16 + ml] = acc[mt][nt][r];
    __syncthreads();

    // packed bf16-pair store, coalesced
    {
        const int row = t >> 1;
        const int half = t & 1;
        const int gr = row0 + row;
        if (gr < N_NODES) {
            u32 ov[32];
            #pragma unroll
            for (int j = 0; j < 32; j++)
                ov[j] = pack_bf16x2(epi[row][half * 64 + 2 * j],
                                    epi[row][half * 64 + 2 * j + 1]);
            u32* op = pre + ((size_t)s * N_NODES + gr) * 64 + half * 32;
            #pragma unroll
            for (int j = 0; j < 8; j++)
                __builtin_nontemporal_store(*(u32x4*)&ov[j * 4], (u32x4*)(op + j * 4));
        }
    }
}

// ---------------------------------------------------------------------------
// Binscatter body: R13-verified except bin_cursor now holds COUNTS (zeroed
// by memset); run base = b*CAP + old count. Block-local contiguous runs ->
// coalesced writes (R8 lesson).
// ---------------------------------------------------------------------------
static __device__ __forceinline__ void scatter_body(char* smem, int bidx,
                                                    const int* __restrict__ rows,
                                                    const int* __restrict__ cols,
                                                    const float* __restrict__ vals,
                                                    int* __restrict__ bin_cursor,
                                                    u32x2* __restrict__ edata) {
    int* lcnt = (int*)smem;
    int* lbase = lcnt + NBINS;
    const int t = threadIdx.x;
    for (int i = t; i < NBINS; i += 256) lcnt[i] = 0;
    __syncthreads();

    const int base = bidx * SC_CHUNK;
    int bin[SC_EPT], lpos[SC_EPT];
    u32x2 pay[SC_EPT];
    #pragma unroll
    for (int j = 0; j < SC_EPT; j++) {
        const int i = base + j * 256 + t;
        if (i < E_TOT) {
            const int r = __builtin_nontemporal_load(rows + i);
            const int c = __builtin_nontemporal_load(cols + i);
            const float v = __builtin_nontemporal_load(vals + i);
            const int b = r >> BSHIFT;
            bin[j] = b;
            lpos[j] = atomicAdd(&lcnt[b], 1);
            pay[j].x = (u32)(c + ((i >= N_EDGES) ? N_NODES : 0)) |
                       ((u32)(r & (BIN_ROWS - 1)) << 18);
            pay[j].y = __float_as_uint(v);
        } else {
            bin[j] = -1;
        }
    }
    __syncthreads();
    for (int b = t; b < NBINS; b += 256) {
        const int c = lcnt[b];
        if (c) lbase[b] = b * CAP + atomicAdd(&bin_cursor[b], c);
    }
    __syncthreads();
    #pragma unroll
    for (int j = 0; j < SC_EPT; j++) {
        if (bin[j] >= 0) edata[lbase[bin[j]] + lpos[j]] = pay[j];
    }
}

// ---------------------------------------------------------------------------
// Binsort body: R13-verified except cnt = min(bin_cursor[b], CAP) (counts,
// not base-offset cursors). In-place via LDS stage; emits {beg,end} per row.
// ---------------------------------------------------------------------------
static __device__ __forceinline__ void sort_body(char* smem, int b,
                                                 u32x2* __restrict__ edata,
                                                 const int* __restrict__ bin_cursor,
                                                 int2* __restrict__ rbe) {
    u32x2* ebuf = (u32x2*)smem;                    // CAP * 8 = 36,864 B
    int* rcnt = (int*)(smem + CAP * 8);            // 512 B
    int* rscan = rcnt + BIN_ROWS;                  // 512 B
    const int t = threadIdx.x;
    const int beg = b * CAP;
    const int cnt = min(bin_cursor[b], CAP);

    for (int e = t; e < cnt; e += 256)
        ebuf[e] = __builtin_nontemporal_load(edata + beg + e);
    if (t < BIN_ROWS) rcnt[t] = 0;
    __syncthreads();

    for (int e = t; e < cnt; e += 256)
        atomicAdd(&rcnt[ebuf[e].x >> 18], 1);
    __syncthreads();

    const int v = (t < BIN_ROWS) ? rcnt[t] : 0;
    if (t < BIN_ROWS) rscan[t] = v;
    __syncthreads();
    #pragma unroll
    for (int off = 1; off < BIN_ROWS; off <<= 1) {
        const int u = (t < BIN_ROWS && t >= off) ? rscan[t - off] : 0;
        __syncthreads();
        if (t < BIN_ROWS) rscan[t] += u;
        __syncthreads();
    }
    if (t < BIN_ROWS) {
        const int ex = rscan[t] - v;
        rcnt[t] = ex;                       // reuse as cursor
        const int row = b * BIN_ROWS + t;
        if (row < N_NODES) {
            int2 be;
            be.x = beg + ex;
            be.y = beg + ex + v;
            rbe[row] = be;
        }
    }
    __syncthreads();
    for (int e = t; e < cnt; e += 256) {
        const u32x2 d = ebuf[e];
        const int pos = beg + atomicAdd(&rcnt[d.x >> 18], 1);
        u32x2 o;
        o.x = d.x & 0x3FFFFu;
        o.y = d.y;
        edata[pos] = o;
    }
}

// ---------------------------------------------------------------------------
// Launch 1: blocks 0..1 = wconv (w -> wT packed bf16); blocks 2.. =
// binscatter at FULL occupancy (6.25 KB LDS -> ~6 blocks/CU, vs 2 when
// fused with the GEMM in R13). bin_cursor pre-zeroed by memset.
// ---------------------------------------------------------------------------
__global__ __launch_bounds__(256) void scatwconv_kernel(const float* __restrict__ w,
                                                        u32* __restrict__ wTb,
                                                        const int* __restrict__ rows,
                                                        const int* __restrict__ cols,
                                                        const float* __restrict__ vals,
                                                        int* __restrict__ bin_cursor,
                                                        u32x2* __restrict__ edata) {
    __shared__ alignas(16) char smem[SCAT_SMEM];
    const int bid = blockIdx.x;
    if (bid < N_SUP) {
        const int s = bid;
        const int n = threadIdx.x >> 1;
        const int kh = (threadIdx.x & 1) * 64;
        const float* wp = w + (size_t)s * DIN * DOUT + n;
        u32 o[32];
        #pragma unroll
        for (int j = 0; j < 32; j++) {
            const float lo = wp[(size_t)(kh + 2 * j) * DOUT];
            const float hi = wp[(size_t)(kh + 2 * j + 1) * DOUT];
            o[j] = pack_bf16x2(lo, hi);
        }
        u32* op = wTb + ((size_t)s * 128 + n) * 64 + kh / 2;
        #pragma unroll
        for (int j = 0; j < 8; j++)
            *(u32x4*)(op + j * 4) = *(u32x4*)&o[j * 4];
        return;
    }
    scatter_body(smem, bid - N_SUP, rows, cols, vals, bin_cursor, edata);
}

// ---------------------------------------------------------------------------
// Launch 2: bid%3==0 -> GEMM s=0, ==1 -> GEMM s=1, ==2 -> binsort.
// Sort (depends only on scatter) overlaps with BOTH GEMMs (depend only on
// wTb) in one launch: chain shortened 4 -> 3 kernels.
// ---------------------------------------------------------------------------
__global__ __launch_bounds__(256) void gemmsort_kernel(const float* __restrict__ x,
                                                       const u32* __restrict__ wTb,
                                                       u32* __restrict__ pre,
                                                       u32x2* __restrict__ edata,
                                                       const int* __restrict__ bin_cursor,
                                                       int2* __restrict__ rbe) {
    __shared__ alignas(16) char smem[GEMM_SMEM];
    const int bid = blockIdx.x;
    const int kind = bid % 3;
    const int idx = bid / 3;
    if (kind == 2) sort_body(smem, idx, edata, bin_cursor, rbe);
    else           gemm_body(smem, idx, kind, x, wTb, pre);
}

// ---------------------------------------------------------------------------
// Gather-accumulate: BYTE-IDENTICAL to R9/R13 (verified 128 us, at the
// ~10.4 B/cyc/CU narrow-coalesced random-access roofline).
// ---------------------------------------------------------------------------
__global__ __launch_bounds__(256, 6) void gather_kernel(const u32* __restrict__ pre,
                                                        const u32x2* __restrict__ edata,
                                                        const int2* __restrict__ rbe,
                                                        const float* __restrict__ bias,
                                                        float* __restrict__ out) {
    const int lane = threadIdx.x & 63;
    const int wid = threadIdx.x >> 6;
    const int row = blockIdx.x * 4 + wid;
    if (row >= N_NODES) return;

    const int2 be = rbe[row];
    int e = be.x;
    const int end = be.y;

    float ax = 0.f, ay = 0.f;

    if (e + 8 <= end) {
        u32x2 d[8];
        #pragma unroll
        for (int j = 0; j < 8; j++)
            d[j] = __builtin_nontemporal_load(edata + e + j);
        for (;;) {
            u32 u[8];
            #pragma unroll
            for (int j = 0; j < 8; j++)
                u[j] = pre[(u32)((d[j].x << 6) + (u32)lane)];
            const int en = e + 8;
            const bool more = (en + 8 <= end);   // wave-uniform
            u32x2 dn[8];
            if (more) {
                #pragma unroll
                for (int j = 0; j < 8; j++)
                    dn[j] = __builtin_nontemporal_load(edata + en + j);
            }
            #pragma unroll
            for (int j = 0; j < 8; j++) {
                const float v = __uint_as_float(d[j].y);
                ax = fmaf(v, __uint_as_float(u[j] << 16), ax);
                ay = fmaf(v, __uint_as_float(u[j] & 0xFFFF0000u), ay);
            }
            e = en;
            if (!more) break;
            #pragma unroll
            for (int j = 0; j < 8; j++) d[j] = dn[j];
        }
    }
    // mid: 4 edges per batch
    for (; e + 4 <= end; e += 4) {
        u32x2 d[4];
        #pragma unroll
        for (int j = 0; j < 4; j++)
            d[j] = __builtin_nontemporal_load(edata + e + j);
        u32 u[4];
        #pragma unroll
        for (int j = 0; j < 4; j++)
            u[j] = pre[(u32)((d[j].x << 6) + (u32)lane)];
        #pragma unroll
        for (int j = 0; j < 4; j++) {
            const float v = __uint_as_float(d[j].y);
            ax = fmaf(v, __uint_as_float(u[j] << 16), ax);
            ay = fmaf(v, __uint_as_float(u[j] & 0xFFFF0000u), ay);
        }
    }
    // tail
    for (; e < end; e++) {
        const u32x2 d = __builtin_nontemporal_load(edata + e);
        const u32 u = pre[(u32)((d.x << 6) + (u32)lane)];
        const float v = __uint_as_float(d.y);
        ax = fmaf(v, __uint_as_float(u << 16), ax);
        ay = fmaf(v, __uint_as_float(u & 0xFFFF0000u), ay);
    }

    const float2 b = *(const float2*)(bias + lane * 2);
    f32x2 r;
    r.x = fmaxf(ax + b.x, 0.f);
    r.y = fmaxf(ay + b.y, 0.f);
    __builtin_nontemporal_store(r, (f32x2*)(out + (size_t)row * DOUT + lane * 2));
}

extern "C" void kernel_launch(void* const* d_in, const int* in_sizes, int n_in,
                              void* d_out, int out_size, void* d_ws, size_t ws_size,
                              hipStream_t stream) {
    (void)in_sizes; (void)n_in; (void)out_size; (void)ws_size;
    const float* x        = (const float*)d_in[0];   // [N, 128]
    const float* w        = (const float*)d_in[1];   // [2, 128, 128]
    const float* bias     = (const float*)d_in[2];   // [128]
    const float* sup_vals = (const float*)d_in[3];   // [2, E] flat
    const int*   sup_rows = (const int*)d_in[4];     // [2, E] flat
    const int*   sup_cols = (const int*)d_in[5];     // [2, E] flat
    float* out = (float*)d_out;                      // [N, 128]

    // ws layout: pre | edata (padded bins) | rbe | bin_cursor | wTb (~81 MB)
    char* ws = (char*)d_ws;
    u32*   pre       = (u32*)ws;                                        // 51.2 MB
    u32x2* edata     = (u32x2*)(ws + (size_t)N_SUP * N_NODES * 64 * 4); // 28.8 MB
    int2*  rbe       = (int2*)((char*)edata + (size_t)NBINS * CAP * 8); // 800 KB
    int*   bin_cursor= (int*)(rbe + N_NODES);                           // NBINS
    u32*   wTb       = (u32*)(bin_cursor + NBINS + 2);                  // 64 KB

    // 1. zero per-bin counts (scatter adds b*CAP itself)
    (void)hipMemsetAsync(bin_cursor, 0, NBINS * sizeof(int), stream);
    // 2. wconv (2 blocks) + binscatter at full occupancy
    scatwconv_kernel<<<N_SUP + NBLK_SC, 256, 0, stream>>>(w, wTb, sup_rows, sup_cols,
                                                          sup_vals, bin_cursor, edata);
    // 3. GEMM s=0 + GEMM s=1 + binsort in one launch (bid%3 interleave)
    gemmsort_kernel<<<3 * NBLK_GEMM, 256, 0, stream>>>(x, wTb, pre, edata,
                                                       bin_cursor, rbe);
    // 4. row gather + bias + ReLU (no atomics)
    gather_kernel<<<(N_NODES + 3) / 4, 256, 0, stream>>>(pre, edata, rbe, bias, out);
}